// Round 1
// baseline (2021.753 us; speedup 1.0000x reference)
//
#include <hip/hip_runtime.h>
#include <math.h>

#define N_ROWS 65536
#define K_CODES 4096
#define DIM 64
#define BK 128   // codes per LDS tile: 128*64*4 = 32 KB

// ---------------------------------------------------------------------------
// Kernel A: e_sq[k] = sum_d embed[k][d]^2   (4096 values into d_ws)
// ---------------------------------------------------------------------------
__global__ __launch_bounds__(256) void esq_kernel(const float* __restrict__ embed,
                                                  float* __restrict__ esq) {
    int k = blockIdx.x * blockDim.x + threadIdx.x;
    if (k >= K_CODES) return;
    const float4* e4 = (const float4*)(embed + (size_t)k * DIM);
    float s0 = 0.f, s1 = 0.f, s2 = 0.f, s3 = 0.f;
#pragma unroll
    for (int i = 0; i < DIM / 4; ++i) {
        float4 v = e4[i];
        s0 = fmaf(v.x, v.x, s0);
        s1 = fmaf(v.y, v.y, s1);
        s2 = fmaf(v.z, v.z, s2);
        s3 = fmaf(v.w, v.w, s3);
    }
    esq[k] = (s0 + s1) + (s2 + s3);
}

// ---------------------------------------------------------------------------
// Kernel B: per-row argmin_k (e_sq[k] - 2 * <x_row, e_k>), then gather code.
// One thread per row; embed tiled through LDS; x row held in 64 VGPRs.
// ---------------------------------------------------------------------------
__global__ __launch_bounds__(256, 1) void vq_kernel(const float* __restrict__ x,
                                                    const float* __restrict__ embed,
                                                    const float* __restrict__ esq,
                                                    float* __restrict__ out_q,
                                                    float* __restrict__ out_ind) {
    __shared__ float lds_e[BK * DIM];   // 32 KB
    __shared__ float lds_esq[BK];       // 512 B

    const int row = blockIdx.x * blockDim.x + threadIdx.x;

    // Load this thread's x row into registers (16 x float4 = 64 VGPRs).
    float xr[DIM];
    {
        const float4* xp = (const float4*)(x + (size_t)row * DIM);
#pragma unroll
        for (int i = 0; i < DIM / 4; ++i) {
            float4 v = xp[i];
            xr[4 * i + 0] = v.x;
            xr[4 * i + 1] = v.y;
            xr[4 * i + 2] = v.z;
            xr[4 * i + 3] = v.w;
        }
    }

    float best = INFINITY;
    int bidx = 0;

    for (int t = 0; t < K_CODES / BK; ++t) {
        __syncthreads();  // protect previous tile's readers
        // Cooperative stage: BK*DIM floats = 2048 float4 / 256 threads = 8 each.
        {
            const float4* src = (const float4*)(embed + (size_t)t * BK * DIM);
            float4* dst = (float4*)lds_e;
#pragma unroll
            for (int i = 0; i < (BK * DIM / 4) / 256; ++i)
                dst[threadIdx.x + i * 256] = src[threadIdx.x + i * 256];
            if (threadIdx.x < BK / 4) {
                ((float4*)lds_esq)[threadIdx.x] =
                    ((const float4*)(esq + t * BK))[threadIdx.x];
            }
        }
        __syncthreads();

#pragma unroll 2
        for (int k = 0; k < BK; ++k) {
            const float4* ek = (const float4*)(lds_e + k * DIM);
            float d0 = 0.f, d1 = 0.f, d2 = 0.f, d3 = 0.f;
#pragma unroll
            for (int i = 0; i < DIM / 4; ++i) {
                float4 v = ek[i];  // wave-uniform address -> LDS broadcast
                d0 = fmaf(xr[4 * i + 0], v.x, d0);
                d1 = fmaf(xr[4 * i + 1], v.y, d1);
                d2 = fmaf(xr[4 * i + 2], v.z, d2);
                d3 = fmaf(xr[4 * i + 3], v.w, d3);
            }
            float key = fmaf(-2.0f, (d0 + d1) + (d2 + d3), lds_esq[k]);
            if (key < best) {
                best = key;
                bidx = t * BK + k;
            }
        }
    }

    // Epilogue: index (as float, exact for < 2^24) + row gather of the code.
    out_ind[row] = (float)bidx;
    const float4* src = (const float4*)(embed + (size_t)bidx * DIM);
    float4* dst = (float4*)(out_q + (size_t)row * DIM);
#pragma unroll
    for (int i = 0; i < DIM / 4; ++i) dst[i] = src[i];
}

// ---------------------------------------------------------------------------
extern "C" void kernel_launch(void* const* d_in, const int* in_sizes, int n_in,
                              void* d_out, int out_size, void* d_ws, size_t ws_size,
                              hipStream_t stream) {
    const float* x = (const float*)d_in[0];      // [N, D] fp32
    const float* embed = (const float*)d_in[1];  // [1, K, D] fp32
    float* out = (float*)d_out;                  // [N*D quantize][N indices]
    float* esq = (float*)d_ws;                   // K floats scratch

    esq_kernel<<<K_CODES / 256, 256, 0, stream>>>(embed, esq);
    vq_kernel<<<N_ROWS / 256, 256, 0, stream>>>(
        x, embed, esq, out, out + (size_t)N_ROWS * DIM);
}

// Round 2
// 478.180 us; speedup vs baseline: 4.2280x; 4.2280x over previous
//
#include <hip/hip_runtime.h>
#include <math.h>

#define N_ROWS 65536
#define K_CODES 4096
#define DIM 64
#define BK 128          // codes per LDS tile: 128*64*4 = 32 KB
#define K_CHUNKS 4
#define CODES_PER_CHUNK (K_CODES / K_CHUNKS)   // 1024
#define ROWS_PER_BLOCK 512                      // 256 threads x 2 rows
#define ROW_GROUPS (N_ROWS / ROWS_PER_BLOCK)    // 128

// ---------------------------------------------------------------------------
// Kernel A: e_sq[k] = sum_d embed[k][d]^2
// ---------------------------------------------------------------------------
__global__ __launch_bounds__(256) void esq_kernel(const float* __restrict__ embed,
                                                  float* __restrict__ esq) {
    int k = blockIdx.x * blockDim.x + threadIdx.x;
    if (k >= K_CODES) return;
    const float4* e4 = (const float4*)(embed + (size_t)k * DIM);
    float s0 = 0.f, s1 = 0.f, s2 = 0.f, s3 = 0.f;
#pragma unroll
    for (int i = 0; i < DIM / 4; ++i) {
        float4 v = e4[i];
        s0 = fmaf(v.x, v.x, s0);
        s1 = fmaf(v.y, v.y, s1);
        s2 = fmaf(v.z, v.z, s2);
        s3 = fmaf(v.w, v.w, s3);
    }
    esq[k] = (s0 + s1) + (s2 + s3);
}

// ---------------------------------------------------------------------------
// Kernel B: partial argmin over one K-chunk for 2 rows per thread.
// grid = ROW_GROUPS * K_CHUNKS blocks; 2 blocks/CU (launch_bounds caps VGPR).
// ---------------------------------------------------------------------------
__global__ __launch_bounds__(256, 2) void vq_partial(const float* __restrict__ x,
                                                     const float* __restrict__ embed,
                                                     const float* __restrict__ esq,
                                                     float* __restrict__ keys,
                                                     int* __restrict__ idxs) {
    __shared__ float lds_e[BK * DIM];   // 32 KB
    __shared__ float lds_q[BK];

    const int kc = blockIdx.x & (K_CHUNKS - 1);
    const int rg = blockIdx.x >> 2;     // log2(K_CHUNKS)
    const int t = threadIdx.x;
    const int rowA = rg * ROWS_PER_BLOCK + t;
    const int rowB = rowA + 256;
    const int kbase = kc * CODES_PER_CHUNK;

    // Two x rows in registers: 2 x 64 = 128 VGPRs.
    float xa[DIM], xb[DIM];
    {
        const float4* pa = (const float4*)(x + (size_t)rowA * DIM);
        const float4* pb = (const float4*)(x + (size_t)rowB * DIM);
#pragma unroll
        for (int i = 0; i < DIM / 4; ++i) {
            float4 va = pa[i], vb = pb[i];
            xa[4 * i + 0] = va.x; xa[4 * i + 1] = va.y;
            xa[4 * i + 2] = va.z; xa[4 * i + 3] = va.w;
            xb[4 * i + 0] = vb.x; xb[4 * i + 1] = vb.y;
            xb[4 * i + 2] = vb.z; xb[4 * i + 3] = vb.w;
        }
    }

    float bestA = INFINITY, bestB = INFINITY;
    int ia = 0, ib = 0;

    for (int tile = 0; tile < CODES_PER_CHUNK / BK; ++tile) {
        __syncthreads();  // protect previous tile's readers
        {
            const float4* src =
                (const float4*)(embed + (size_t)(kbase + tile * BK) * DIM);
            float4* dst = (float4*)lds_e;
#pragma unroll
            for (int i = 0; i < (BK * DIM / 4) / 256; ++i)
                dst[t + i * 256] = src[t + i * 256];
            if (t < BK / 4)
                ((float4*)lds_q)[t] =
                    ((const float4*)(esq + kbase + tile * BK))[t];
        }
        __syncthreads();

#pragma unroll 1
        for (int k = 0; k < BK; ++k) {
            const float4* ek = (const float4*)(lds_e + k * DIM);  // uniform -> broadcast
            float a0 = 0.f, a1 = 0.f, a2 = 0.f, a3 = 0.f;
            float b0 = 0.f, b1 = 0.f, b2 = 0.f, b3 = 0.f;
#pragma unroll
            for (int i = 0; i < DIM / 4; ++i) {
                float4 v = ek[i];
                a0 = fmaf(xa[4 * i + 0], v.x, a0);
                a1 = fmaf(xa[4 * i + 1], v.y, a1);
                a2 = fmaf(xa[4 * i + 2], v.z, a2);
                a3 = fmaf(xa[4 * i + 3], v.w, a3);
                b0 = fmaf(xb[4 * i + 0], v.x, b0);
                b1 = fmaf(xb[4 * i + 1], v.y, b1);
                b2 = fmaf(xb[4 * i + 2], v.z, b2);
                b3 = fmaf(xb[4 * i + 3], v.w, b3);
            }
            float eq = lds_q[k];
            float ka = fmaf(-2.0f, (a0 + a1) + (a2 + a3), eq);
            float kb = fmaf(-2.0f, (b0 + b1) + (b2 + b3), eq);
            int gc = kbase + tile * BK + k;
            if (ka < bestA) { bestA = ka; ia = gc; }
            if (kb < bestB) { bestB = kb; ib = gc; }
        }
    }

    keys[(size_t)kc * N_ROWS + rowA] = bestA;
    keys[(size_t)kc * N_ROWS + rowB] = bestB;
    idxs[(size_t)kc * N_ROWS + rowA] = ia;
    idxs[(size_t)kc * N_ROWS + rowB] = ib;
}

// ---------------------------------------------------------------------------
// Kernel C: merge the K_CHUNKS candidates per row, write index + gather code.
// Strict < scanning chunks in ascending index order == numpy first-min rule.
// ---------------------------------------------------------------------------
__global__ __launch_bounds__(256) void vq_merge(const float* __restrict__ embed,
                                                const float* __restrict__ keys,
                                                const int* __restrict__ idxs,
                                                float* __restrict__ out_q,
                                                float* __restrict__ out_ind) {
    int r = blockIdx.x * blockDim.x + threadIdx.x;
    if (r >= N_ROWS) return;
    float best = keys[r];
    int bi = idxs[r];
#pragma unroll
    for (int c = 1; c < K_CHUNKS; ++c) {
        float k2 = keys[(size_t)c * N_ROWS + r];
        int i2 = idxs[(size_t)c * N_ROWS + r];
        if (k2 < best) { best = k2; bi = i2; }
    }
    out_ind[r] = (float)bi;
    const float4* src = (const float4*)(embed + (size_t)bi * DIM);
    float4* dst = (float4*)(out_q + (size_t)r * DIM);
#pragma unroll
    for (int i = 0; i < DIM / 4; ++i) dst[i] = src[i];
}

// ---------------------------------------------------------------------------
extern "C" void kernel_launch(void* const* d_in, const int* in_sizes, int n_in,
                              void* d_out, int out_size, void* d_ws, size_t ws_size,
                              hipStream_t stream) {
    const float* x = (const float*)d_in[0];      // [N, D] fp32
    const float* embed = (const float*)d_in[1];  // [1, K, D] fp32
    float* out = (float*)d_out;                  // [N*D quantize][N indices]

    float* esq = (float*)d_ws;                               // K floats
    float* keys = esq + K_CODES;                             // K_CHUNKS * N floats
    int* idxs = (int*)(keys + (size_t)K_CHUNKS * N_ROWS);    // K_CHUNKS * N ints

    esq_kernel<<<K_CODES / 256, 256, 0, stream>>>(embed, esq);
    vq_partial<<<ROW_GROUPS * K_CHUNKS, 256, 0, stream>>>(x, embed, esq, keys, idxs);
    vq_merge<<<N_ROWS / 256, 256, 0, stream>>>(embed, keys, idxs, out,
                                               out + (size_t)N_ROWS * DIM);
}